// Round 10
// baseline (67.598 us; speedup 1.0000x reference)
//
#include <hip/hip_runtime.h>
#include <hip/hip_bf16.h>

// Problem constants (from reference)
#define UNITS 512
#define CONN  512
#define SEQL  32

typedef __hip_bfloat16 bf16;
typedef __attribute__((ext_vector_type(8))) short short8;   // 8 bf16 = MFMA A/B frag
typedef __attribute__((ext_vector_type(4))) float floatx4;  // MFMA C/D frag

// out[b,u] = relu( sum_c x[b,c] * kernel[u] * dendriticW[dendrites[u,c], u] + bias[u] )
// == 512^3 GEMM with gather-built weights. fp32 I/O; x,W quantized to bf16 for
// MFMA (absmax 1.95e-3 vs 9.84e-3 threshold, measured R4-R9).
//
// Session ledger: R4 67.2 / R5 fused 69.7 / R6 73.3 / R7 two-kernel 66.6 /
// R8 coop 142.9 (grid.sync ~60us - never again) / R9 K-split 67.1.
// ~50 us of the window is harness-fixed (256 MiB d_ws poison at 83% HBM peak).
//
// R10 = R5's single-launch fused structure + R7's LDS-staged dW table (the
// fix the fused line never received): the 8x W-tile rebuild redundancy now
// costs only LDS lookups, not scattered 32-line L2 gathers. One launch, no
// d_ws, W lives in LDS (no global round-trip).
//   Block = 16 units x 64 batches, grid 32x8, 256 threads.
//   Build: stage 16 dW columns (2 KB, coalesced) -> gather W tile into LDS
//          in MFMA B-frag order (wl[kb][lane], proven R5 layout).
//   Compute: 4 waves x one 16x16 MFMA tile, K=512 unrolled, x from global
//          fp32 + in-reg cvt (proven R5/R6).
// Frag layouts (m89/m92-verified): A[m=lane&15][k=(lane>>4)*8+j]; B idem from
// B^T rows; C/D col=lane&15, row=(lane>>4)*4+reg.

union cv8 { bf16 h[8]; short8 v; };

__device__ __forceinline__ short8 cvt8(const float* p) {
    const float4 f0 = ((const float4*)p)[0];
    const float4 f1 = ((const float4*)p)[1];
    cv8 a;
    a.h[0] = __float2bfloat16(f0.x); a.h[1] = __float2bfloat16(f0.y);
    a.h[2] = __float2bfloat16(f0.z); a.h[3] = __float2bfloat16(f0.w);
    a.h[4] = __float2bfloat16(f1.x); a.h[5] = __float2bfloat16(f1.y);
    a.h[6] = __float2bfloat16(f1.z); a.h[7] = __float2bfloat16(f1.w);
    return a.v;
}

__global__ __launch_bounds__(256) void dendriter_fused_v2(
    const float* __restrict__ x,     // [batch*CONN] fp32
    const float* __restrict__ kern,  // [UNITS] fp32
    const float* __restrict__ dW,    // [SEQL*UNITS] fp32
    const float* __restrict__ bias,  // [UNITS] fp32
    const int*   __restrict__ dend,  // [UNITS*CONN] int32
    float* __restrict__ out)         // [batch*UNITS] fp32
{
    __shared__ short8 wl[16][65];        // W tile, B-frag order (R5 layout)
    __shared__ float  table[16][33];     // dW columns; bank=(ul+seg)%32 spread

    const int t  = threadIdx.x;          // 0..255
    const int ut = blockIdx.x * 16;      // unit tile
    const int bt = blockIdx.y * 64;      // batch tile

    // ---- stage the block's 16 dW columns: 512 floats, 2 loads/thread ----
#pragma unroll
    for (int j = 0; j < 2; ++j) {
        const int idx = t + j * 256;     // 0..511
        const int seg = idx >> 4;        // 0..31
        const int ul  = idx & 15;        // 0..15
        table[ul][seg] = dW[seg * UNITS + ut + ul];  // 64B-contig per 16 thr
    }
    __syncthreads();

    // ---- build phase: W tile -> LDS in B-frag order ----
    {
        const int ul  = t >> 4;          // unit_local 0..15
        const int cg0 = (t & 15) * 4;    // 4 groups of 8 conns
        const float kv = kern[ut + ul];
        const int4* dp = (const int4*)(dend + (ut + ul) * CONN + cg0 * 8);
#pragma unroll
        for (int j = 0; j < 4; ++j) {
            const int4 s0 = dp[2 * j];
            const int4 s1 = dp[2 * j + 1];
            const int segs[8] = {s0.x, s0.y, s0.z, s0.w, s1.x, s1.y, s1.z, s1.w};
            cv8 w;
#pragma unroll
            for (int i = 0; i < 8; ++i)  // LDS lookup (was: scattered L2 gather)
                w.h[i] = __float2bfloat16(kv * table[ul][segs[i]]);
            const int cg = cg0 + j;      // c = cg*8 + i = kb*32 + q*8 + i
            wl[cg >> 2][ul | ((cg & 3) << 4)] = w.v;
        }
    }
    __syncthreads();

    // ---- compute phase: 1 wave per 16x16 out tile ----
    const int lane = t & 63;
    const int wv   = t >> 6;             // 0..3 -> batch sub-tile
    const int m = lane & 15;
    const int q = lane >> 4;
    const int btw = bt + wv * 16;

    const float* xrow = x + (size_t)(btw + m) * CONN + q * 8;
    floatx4 acc = {0.f, 0.f, 0.f, 0.f};
#pragma unroll
    for (int kb = 0; kb < 16; ++kb) {
        const short8 a = cvt8(xrow + kb * 32);       // 2x float4 + cvt
        const short8 b = wl[kb][lane];               // 16B/lane, conflict-free
        acc = __builtin_amdgcn_mfma_f32_16x16x32_bf16(a, b, acc, 0, 0, 0);
    }

    const float bu = bias[ut + m];
#pragma unroll
    for (int r = 0; r < 4; ++r) {
        float v = acc[r] + bu;
        v = v > 0.f ? v : 0.f;
        out[(size_t)(btw + q * 4 + r) * UNITS + ut + m] = v;
    }
}

extern "C" void kernel_launch(void* const* d_in, const int* in_sizes, int n_in,
                              void* d_out, int out_size, void* d_ws, size_t ws_size,
                              hipStream_t stream) {
    // setup_inputs() order: x, kernel, dendriticW, bias, dendrites — all fp32
    const float* x    = (const float*)d_in[0];
    const float* kern = (const float*)d_in[1];
    const float* dW   = (const float*)d_in[2];
    const float* bias = (const float*)d_in[3];
    const int*   dend = (const int*)  d_in[4];
    float* out = (float*)d_out;

    const int batch = in_sizes[0] / CONN;   // 512
    dendriter_fused_v2<<<dim3(UNITS / 16, batch / 64), 256, 0, stream>>>(
        x, kern, dW, bias, dend, out);
}